// Round 1
// baseline (168.805 us; speedup 1.0000x reference)
//
#include <hip/hip_runtime.h>

// 21-qubit batched (B=4) state-vector simulator.
// State: 4 x 2^21 f32 in d_ws (32 MB). Qubit w <-> bit (20-w) of flat index.
// Pass schedule (each pass = one tiling of 2^14-amp tiles, gates in registers):
//   k_init : product state of RY(x) folded with layer-1 CNOTs (20,19)..(14,13)  [write-only]
//   k_L(wj): CNOTs bits (13,12)..(1,0), RY wj on bits 1..13 (qubits 7..19)
//   k_H(wj): CNOT (0,20), RY wj qubits {20,0..6}, next-layer CNOTs (20,19)..(14,13)
//   k_Hfin : CNOT (0,20), RY w2 qubits {20,0..6}, probs + Z-expectation partials
//   k_red  : deterministic partial-sum reduction -> out[4][21]

#define NQ 21

template<int Q>
__device__ __forceinline__ void ry64(float* v, float c, float s) {
#pragma unroll
  for (int k = 0; k < 32; ++k) {
    int l0 = ((k >> Q) << (Q + 1)) | (k & ((1 << Q) - 1));
    int l1 = l0 | (1 << Q);
    float a0 = v[l0], a1 = v[l1];
    v[l0] = c * a0 - s * a1;
    v[l1] = s * a0 + c * a1;
  }
}

template<int C, int T>
__device__ __forceinline__ void cnot64(float* v) {
  constexpr int lo = (C < T) ? C : T;
  constexpr int hi = (C < T) ? T : C;
#pragma unroll
  for (int k = 0; k < 16; ++k) {
    int i1 = ((k >> lo) << (lo + 1)) | (k & ((1 << lo) - 1));
    int i2 = ((i1 >> hi) << (hi + 1)) | (i1 & ((1 << hi) - 1));
    int a = i2 | (1 << C);      // control = 1, target = 0
    int b = a | (1 << T);
    float tmp = v[a]; v[a] = v[b]; v[b] = tmp;
  }
}

#define SHC(q) __shfl(cv, (q)), __shfl(sv, (q))

// ---------------- init: product state + high CNOT chain folded in ----------------
__global__ __launch_bounds__(256) void k_init(const float* __restrict__ x,
                                              float* __restrict__ st) {
  __shared__ float cs[32], sn[32];
  __shared__ __align__(16) float low[64];
  __shared__ float high[256];
  const int tid = threadIdx.x;
  const int b = blockIdx.x >> 7, t = blockIdx.x & 127;
  if (tid < NQ) {
    float ss, cc;
    sincosf(0.5f * x[b * NQ + tid], &ss, &cc);
    cs[tid] = cc; sn[tid] = ss;
  }
  __syncthreads();
  if (tid < 64) {
    float p = 1.f;
#pragma unroll
    for (int gb = 0; gb < 6; ++gb) p *= ((tid >> gb) & 1) ? sn[20 - gb] : cs[20 - gb];
    low[tid] = p;
  }
  {
    // pre-image under layer-1 CNOT chain on bits 13..20: h ^ (h>>1)
    int hp = tid ^ (tid >> 1);
    float p = 1.f;
#pragma unroll
    for (int j = 0; j < 8; ++j) p *= ((hp >> j) & 1) ? sn[7 - j] : cs[7 - j];
    high[tid] = p;
  }
  float pf = 1.f;
#pragma unroll
  for (int k = 0; k < 7; ++k) pf *= ((t >> k) & 1) ? sn[14 - k] : cs[14 - k];
  __syncthreads();
  float4* g4 = reinterpret_cast<float4*>(st) + ((size_t)b << 19);
  const float4* low4 = reinterpret_cast<const float4*>(low);
#pragma unroll
  for (int i = 0; i < 16; ++i) {
    int j = tid + (i << 8);           // [0,4096) float4 within tile
    float hv = high[j >> 4] * pf;
    float4 lv = low4[j & 15];
    float4 o;
    o.x = lv.x * hv; o.y = lv.y * hv; o.z = lv.z * hv; o.w = lv.w * hv;
    g4[(j & 15) | (t << 4) | ((j >> 4) << 11)] = o;
  }
}

// ---------------- L pass: contiguous tile, bits 0..13 ----------------
__global__ __launch_bounds__(256, 2) void k_L(const float* __restrict__ w,
                                              float* __restrict__ st) {
  __shared__ __align__(16) float s[16384];
  const int tid = threadIdx.x;
  const int b = blockIdx.x >> 7, t = blockIdx.x & 127;
  float cv = 1.f, sv = 0.f;
  { int lane = tid & 63; if (lane < NQ) sincosf(0.5f * w[lane], &sv, &cv); }
  float4* g4 = reinterpret_cast<float4*>(st) + ((size_t)b << 19) + ((size_t)t << 12);
  float v[64];
  float4* v4 = reinterpret_cast<float4*>(v);
  float4* s4 = reinterpret_cast<float4*>(s);

  // sweep alpha: bits {0,1,10..13}; load straight from global (coalesced)
#pragma unroll
  for (int rr = 0; rr < 16; ++rr) v4[rr] = g4[tid + (rr << 8)];
  cnot64<5, 4>(v); cnot64<4, 3>(v); cnot64<3, 2>(v);   // C(13,12) C(12,11) C(11,10)
  ry64<5>(v, SHC(7)); ry64<4>(v, SHC(8)); ry64<3>(v, SHC(9));
#pragma unroll
  for (int rr = 0; rr < 16; ++rr) s4[tid + (rr << 8)] = v4[rr];
  __syncthreads();

  // sweep beta: bits {0,1,7..10}
#pragma unroll
  for (int rr = 0; rr < 16; ++rr) v4[rr] = s4[(tid & 31) | (rr << 5) | ((tid >> 5) << 9)];
  cnot64<5, 4>(v); cnot64<4, 3>(v); cnot64<3, 2>(v);   // C(10,9) C(9,8) C(8,7)
  ry64<5>(v, SHC(10)); ry64<4>(v, SHC(11)); ry64<3>(v, SHC(12));
#pragma unroll
  for (int rr = 0; rr < 16; ++rr) s4[(tid & 31) | (rr << 5) | ((tid >> 5) << 9)] = v4[rr];
  __syncthreads();

  // sweep gamma: bits {0,1,4..7}
#pragma unroll
  for (int rr = 0; rr < 16; ++rr) v4[rr] = s4[(tid & 3) | (rr << 2) | ((tid >> 2) << 6)];
  cnot64<5, 4>(v); cnot64<4, 3>(v); cnot64<3, 2>(v);   // C(7,6) C(6,5) C(5,4)
  ry64<5>(v, SHC(13)); ry64<4>(v, SHC(14)); ry64<3>(v, SHC(15));
#pragma unroll
  for (int rr = 0; rr < 16; ++rr) s4[(tid & 3) | (rr << 2) | ((tid >> 2) << 6)] = v4[rr];
  __syncthreads();

  // sweep delta: bits {0..5}; store straight to global
#pragma unroll
  for (int rr = 0; rr < 16; ++rr) v4[rr] = s4[rr | (tid << 4)];
  cnot64<4, 3>(v); cnot64<3, 2>(v); cnot64<2, 1>(v); cnot64<1, 0>(v); // C(4,3)..C(1,0)
  ry64<4>(v, SHC(16)); ry64<3>(v, SHC(17)); ry64<2>(v, SHC(18)); ry64<1>(v, SHC(19));
#pragma unroll
  for (int rr = 0; rr < 16; ++rr) g4[rr | (tid << 4)] = v4[rr];
}

// ---------------- H pass: tile bits {0..5, 13..20}; local 6..13 = global 13..20 ----
__global__ __launch_bounds__(256, 2) void k_H(const float* __restrict__ w,
                                              float* __restrict__ st) {
  __shared__ __align__(16) float s[16384];
  const int tid = threadIdx.x;
  const int b = blockIdx.x >> 7, t = blockIdx.x & 127;
  float cv = 1.f, sv = 0.f;
  { int lane = tid & 63; if (lane < NQ) sincosf(0.5f * w[lane], &sv, &cv); }
  float4* g4 = reinterpret_cast<float4*>(st) + ((size_t)b << 19);
  float v[64];
  float4* v4 = reinterpret_cast<float4*>(v);
  float4* s4 = reinterpret_cast<float4*>(s);
  const int tlo = tid & 15, thi = tid >> 4;

  // sweep A: local bits {0,1,10..13} (r0=l0, r5=l13); load direct from global
#pragma unroll
  for (int rr = 0; rr < 16; ++rr)
    v4[rr] = g4[tlo | (t << 4) | ((thi | (rr << 4)) << 11)];
  cnot64<0, 5>(v);                                  // CNOT(q20 -> q0) = C(bit0, bit20)
  ry64<0>(v, SHC(20)); ry64<5>(v, SHC(0)); ry64<4>(v, SHC(1));
  ry64<3>(v, SHC(2));  ry64<2>(v, SHC(3));
  cnot64<5, 4>(v); cnot64<4, 3>(v); cnot64<3, 2>(v); // next layer C(20,19) C(19,18) C(18,17)
#pragma unroll
  for (int rr = 0; rr < 16; ++rr) s4[tid | (rr << 8)] = v4[rr];
  __syncthreads();

  // sweep B: local bits {0,1,7..10}
#pragma unroll
  for (int rr = 0; rr < 16; ++rr) v4[rr] = s4[(tid & 31) | (rr << 5) | ((tid >> 5) << 9)];
  ry64<4>(v, SHC(4)); ry64<3>(v, SHC(5));
  cnot64<5, 4>(v); cnot64<4, 3>(v);                  // C(17,16) C(16,15)
#pragma unroll
  for (int rr = 0; rr < 16; ++rr) s4[(tid & 31) | (rr << 5) | ((tid >> 5) << 9)] = v4[rr];
  __syncthreads();

  // sweep C: local bits {0,1,5..8}
#pragma unroll
  for (int rr = 0; rr < 16; ++rr) v4[rr] = s4[(tid & 7) | (rr << 3) | ((tid >> 3) << 7)];
  ry64<4>(v, SHC(6));
  cnot64<5, 4>(v); cnot64<4, 3>(v);                  // C(15,14) C(14,13)
#pragma unroll
  for (int rr = 0; rr < 16; ++rr) {
    int l4 = (tid & 7) | (rr << 3) | ((tid >> 3) << 7);
    g4[(l4 & 15) | (t << 4) | ((l4 >> 4) << 11)] = v4[rr];
  }
}

// ---------------- final H pass + measurement ----------------
__global__ __launch_bounds__(256, 2) void k_Hfin(const float* __restrict__ w,
                                                 const float* __restrict__ st,
                                                 float* __restrict__ partial) {
  __shared__ __align__(16) float s[16384];
  const int tid = threadIdx.x;
  const int b = blockIdx.x >> 7, t = blockIdx.x & 127;
  float cv = 1.f, sv = 0.f;
  { int lane = tid & 63; if (lane < NQ) sincosf(0.5f * w[lane], &sv, &cv); }
  const float4* g4 = reinterpret_cast<const float4*>(st) + ((size_t)b << 19);
  float v[64];
  float4* v4 = reinterpret_cast<float4*>(v);
  float4* s4 = reinterpret_cast<float4*>(s);
  const int tlo = tid & 15, thi = tid >> 4;

  // sweep A4: local bits {0,1,10..13}
#pragma unroll
  for (int rr = 0; rr < 16; ++rr)
    v4[rr] = g4[tlo | (t << 4) | ((thi | (rr << 4)) << 11)];
  cnot64<0, 5>(v);
  ry64<0>(v, SHC(20)); ry64<5>(v, SHC(0)); ry64<4>(v, SHC(1));
  ry64<3>(v, SHC(2));  ry64<2>(v, SHC(3));
#pragma unroll
  for (int rr = 0; rr < 16; ++rr) s4[tid | (rr << 8)] = v4[rr];
  __syncthreads();

  // sweep B4: local bits {0,1,7..10}: r0=l0,r1=l1,r2=l7,r3=l8,r4=l9,r5=l10
#pragma unroll
  for (int rr = 0; rr < 16; ++rr) v4[rr] = s4[(tid & 31) | (rr << 5) | ((tid >> 5) << 9)];
  ry64<4>(v, SHC(4)); ry64<3>(v, SHC(5)); ry64<2>(v, SHC(6));
  __syncthreads();   // done with tile; reuse LDS for reduction

  float S = 0, aq20 = 0, aq19 = 0, aq6 = 0, aq5 = 0, aq4 = 0, aq3 = 0;
#pragma unroll
  for (int r = 0; r < 64; ++r) {
    float p = v[r] * v[r];
    S += p;
    aq20 += (r & 1)  ? -p : p;   // r0 = l0  -> gbit0  -> q20
    aq19 += (r & 2)  ? -p : p;   // r1 = l1  -> q19
    aq6  += (r & 4)  ? -p : p;   // r2 = l7  -> gbit14 -> q6
    aq5  += (r & 8)  ? -p : p;   // r3 = l8  -> q5
    aq4  += (r & 16) ? -p : p;   // r4 = l9  -> q4
    aq3  += (r & 32) ? -p : p;   // r5 = l10 -> q3
  }
  float a21[21];
  a21[20] = aq20; a21[19] = aq19; a21[6] = aq6; a21[5] = aq5; a21[4] = aq4; a21[3] = aq3;
  a21[18] = (tid & 1)   ? -S : S;  // l2  -> q18
  a21[17] = (tid & 2)   ? -S : S;  // l3  -> q17
  a21[16] = (tid & 4)   ? -S : S;  // l4  -> q16
  a21[15] = (tid & 8)   ? -S : S;  // l5  -> q15
  a21[7]  = (tid & 16)  ? -S : S;  // l6  -> gbit13 -> q7
  a21[2]  = (tid & 32)  ? -S : S;  // l11 -> gbit18 -> q2
  a21[1]  = (tid & 64)  ? -S : S;  // l12 -> q1
  a21[0]  = (tid & 128) ? -S : S;  // l13 -> q0
  a21[14] = (t & 1)  ? -S : S;     // gbit6  -> q14
  a21[13] = (t & 2)  ? -S : S;
  a21[12] = (t & 4)  ? -S : S;
  a21[11] = (t & 8)  ? -S : S;
  a21[10] = (t & 16) ? -S : S;
  a21[9]  = (t & 32) ? -S : S;
  a21[8]  = (t & 64) ? -S : S;     // gbit12 -> q8

  float* red = s;
#pragma unroll
  for (int q = 0; q < 21; ++q) {
    float val = a21[q];
    val += __shfl_down(val, 32);
    val += __shfl_down(val, 16);
    val += __shfl_down(val, 8);
    val += __shfl_down(val, 4);
    val += __shfl_down(val, 2);
    val += __shfl_down(val, 1);
    if ((tid & 63) == 0) red[q * 4 + (tid >> 6)] = val;
  }
  __syncthreads();
  if (tid < 21)
    partial[blockIdx.x * 21 + tid] =
        red[tid * 4] + red[tid * 4 + 1] + red[tid * 4 + 2] + red[tid * 4 + 3];
}

// ---------------- deterministic final reduction ----------------
__global__ void k_red(const float* __restrict__ partial, float* __restrict__ out) {
  int tid = threadIdx.x;
  if (tid < 84) {
    int b = tid / 21, q = tid % 21;
    float sum = 0.f;
    for (int k = 0; k < 128; ++k) sum += partial[(b * 128 + k) * 21 + q];
    out[tid] = sum;     // tid == b*21 + q
  }
}

extern "C" void kernel_launch(void* const* d_in, const int* in_sizes, int n_in,
                              void* d_out, int out_size, void* d_ws, size_t ws_size,
                              hipStream_t stream) {
  const float* x = (const float*)d_in[0];   // (4,21) f32
  const float* w = (const float*)d_in[1];   // (3,21) f32
  float* out = (float*)d_out;               // (4,21) f32
  float* st = (float*)d_ws;                 // 4 * 2^21 f32
  float* partial = st + ((size_t)4 << 21);  // 512*21 f32
  if (ws_size < ((size_t)4 << 21) * 4 + 512 * 21 * 4) return;

  dim3 grid(512), blk(256);
  k_init<<<grid, blk, 0, stream>>>(x, st);
  k_L   <<<grid, blk, 0, stream>>>(w +  0, st);
  k_H   <<<grid, blk, 0, stream>>>(w +  0, st);
  k_L   <<<grid, blk, 0, stream>>>(w + 21, st);
  k_H   <<<grid, blk, 0, stream>>>(w + 21, st);
  k_L   <<<grid, blk, 0, stream>>>(w + 42, st);
  k_Hfin<<<grid, blk, 0, stream>>>(w + 42, st, partial);
  k_red <<<1, dim3(128), 0, stream>>>(partial, out);
}

// Round 2
// 121.389 us; speedup vs baseline: 1.3906x; 1.3906x over previous
//
#include <hip/hip_runtime.h>

// 21-qubit batched (B=4) state-vector simulator, 6 full passes + reduce.
// State: 4 x 2^21 f32 in d_ws (32 MB). Qubit q <-> bit (20-q) of flat index.
// Tiles: 2^14 amps (64 KB LDS), 512 threads/block, 32 amps/thread,
//        5-bit register windows {l0,l1, m,m+1,m+2}.
// Schedule:
//   k_L<true> : closed-form init (x-RYs + layer-1 high CNOTs folded) + low pass, write-only
//   k_H       : wrap CNOT + high RYs + next-layer high CNOT chain
//   k_L<false>: low CNOT chain + low RYs
//   k_Hfin    : wrap + high RYs + probs + Z partials
//   k_red     : deterministic partial reduction -> out[4][21]
// LDS float4 slots are XOR-swizzled: phys = l4 ^ ((l4>>3)&7)  (bank-spread, involution).

#define NQ 21
#define SW(a) ((a) ^ (((a) >> 3) & 7))
#define SHC(q) __shfl(cv, (q)), __shfl(sv, (q))

template<int Q>
__device__ __forceinline__ void ry32(float* v, float c, float s) {
#pragma unroll
  for (int k = 0; k < 16; ++k) {
    int l0 = ((k >> Q) << (Q + 1)) | (k & ((1 << Q) - 1));
    int l1 = l0 | (1 << Q);
    float a0 = v[l0], a1 = v[l1];
    v[l0] = c * a0 - s * a1;
    v[l1] = s * a0 + c * a1;
  }
}

template<int C, int T>
__device__ __forceinline__ void cnot32(float* v) {
  constexpr int lo = (C < T) ? C : T;
  constexpr int hi = (C < T) ? T : C;
#pragma unroll
  for (int k = 0; k < 8; ++k) {
    int i1 = ((k >> lo) << (lo + 1)) | (k & ((1 << lo) - 1));
    int i2 = ((i1 >> hi) << (hi + 1)) | (i1 & ((1 << hi) - 1));
    int a = i2 | (1 << C);   // control = 1, target = 0
    int b = a | (1 << T);
    float tmp = v[a]; v[a] = v[b]; v[b] = tmp;
  }
}

// logical LDS float4 addresses per sweep (l4 = local_amp_index >> 2, 12 bits)
#define A1 (tid | (rr << 9))
#define A2 ((tid & 0x7F) | (rr << 7) | ((tid >> 7) << 10))
#define A3 ((tid & 0x1F) | (rr << 5) | ((tid >> 5) << 8))
#define A4 ((tid & 7) | (rr << 3) | ((tid >> 3) << 6))
#define A5 ((tid & 1) | (rr << 1) | ((tid >> 1) << 4))
#define A6 (rr | (tid << 3))

// ---------------- L pass: tile = bits 0..13, t = bits 14..20 ----------------
template<bool INIT>
__global__ __launch_bounds__(512, 4) void k_L(const float* __restrict__ x,
                                              const float* __restrict__ w,
                                              float* __restrict__ st) {
  __shared__ __align__(16) float s[16384];
  float4* s4 = reinterpret_cast<float4*>(s);
  const int tid = threadIdx.x;
  const int b = blockIdx.x >> 7, t = blockIdx.x & 127;
  const int lane = tid & 63;
  float cv = 1.f, sv = 0.f;
  if (lane < NQ) sincosf(0.5f * w[lane], &sv, &cv);
  float4* g4 = reinterpret_cast<float4*>(st) + ((size_t)b << 19) + ((size_t)t << 12);
  float v[32];
  float4* v4 = reinterpret_cast<float4*>(v);

  // ---- S1: window {0,1,11,12,13} ----
  if (INIT) {
    // product state after x-RYs, pre-imaged through layer-1 chain C(20,19)..C(14,13)
    float cx = 1.f, sx = 0.f;
    if (lane < NQ) sincosf(0.5f * x[b * NQ + lane], &sx, &cx);
    float Qp = 1.f;
#pragma unroll
    for (int i = 0; i < 9; ++i) {            // tid bit i -> g(2+i) -> qubit 18-i
      float cq = __shfl(cx, 18 - i), sq = __shfl(sx, 18 - i);
      Qp *= ((tid >> i) & 1) ? sq : cq;
    }
    float hfac[2];
#pragma unroll
    for (int bb = 0; bb < 2; ++bb) {         // g13 = bb, h = g[13..20]
      int h = (t << 1) | bb;
      int h0 = h ^ (h >> 1);                 // pre-image of high chain
      float p = 1.f;
#pragma unroll
      for (int j = 0; j < 8; ++j) {          // h0 bit j -> g(13+j) -> qubit 7-j
        float cq = __shfl(cx, 7 - j), sq = __shfl(sx, 7 - j);
        p *= ((h0 >> j) & 1) ? sq : cq;
      }
      hfac[bb] = p;
    }
    float c20 = __shfl(cx, 20), s20 = __shfl(sx, 20), c19 = __shfl(cx, 19), s19 = __shfl(sx, 19);
    float c9  = __shfl(cx, 9),  s9  = __shfl(sx, 9),  c8  = __shfl(cx, 8),  s8  = __shfl(sx, 8);
    float w0t[4], w1t[4];
#pragma unroll
    for (int i = 0; i < 4; ++i) {
      w0t[i] = ((i & 1) ? s20 : c20) * ((i & 2) ? s19 : c19);  // bits g0,g1
      w1t[i] = ((i & 1) ? s9  : c9 ) * ((i & 2) ? s8  : c8 );  // bits g11,g12
    }
#pragma unroll
    for (int r = 0; r < 32; ++r)
      v[r] = hfac[(r >> 4) & 1] * w1t[(r >> 2) & 3] * w0t[r & 3] * Qp;
  } else {
#pragma unroll
    for (int rr = 0; rr < 8; ++rr) v4[rr] = g4[A1];
  }
  cnot32<4, 3>(v); cnot32<3, 2>(v);           // C(13,12) C(12,11)
  ry32<4>(v, SHC(7)); ry32<3>(v, SHC(8));     // RY b13(q7) b12(q8)
#pragma unroll
  for (int rr = 0; rr < 8; ++rr) s4[SW(A1)] = v4[rr];
  __syncthreads();

  // ---- S2: window {0,1,9,10,11} ----
#pragma unroll
  for (int rr = 0; rr < 8; ++rr) v4[rr] = s4[SW(A2)];
  cnot32<4, 3>(v); cnot32<3, 2>(v);           // C(11,10) C(10,9)
  ry32<4>(v, SHC(9)); ry32<3>(v, SHC(10));    // RY b11(q9) b10(q10)
#pragma unroll
  for (int rr = 0; rr < 8; ++rr) s4[SW(A2)] = v4[rr];
  __syncthreads();

  // ---- S3: window {0,1,7,8,9} ----
#pragma unroll
  for (int rr = 0; rr < 8; ++rr) v4[rr] = s4[SW(A3)];
  cnot32<4, 3>(v); cnot32<3, 2>(v);           // C(9,8) C(8,7)
  ry32<4>(v, SHC(11)); ry32<3>(v, SHC(12));   // RY b9(q11) b8(q12)
#pragma unroll
  for (int rr = 0; rr < 8; ++rr) s4[SW(A3)] = v4[rr];
  __syncthreads();

  // ---- S4: window {0,1,5,6,7} ----
#pragma unroll
  for (int rr = 0; rr < 8; ++rr) v4[rr] = s4[SW(A4)];
  cnot32<4, 3>(v); cnot32<3, 2>(v);           // C(7,6) C(6,5)
  ry32<4>(v, SHC(13)); ry32<3>(v, SHC(14));   // RY b7(q13) b6(q14)
#pragma unroll
  for (int rr = 0; rr < 8; ++rr) s4[SW(A4)] = v4[rr];
  __syncthreads();

  // ---- S5: window {0,1,3,4,5} ----
#pragma unroll
  for (int rr = 0; rr < 8; ++rr) v4[rr] = s4[SW(A5)];
  cnot32<4, 3>(v); cnot32<3, 2>(v);           // C(5,4) C(4,3)
  ry32<4>(v, SHC(15)); ry32<3>(v, SHC(16));   // RY b5(q15) b4(q16)
#pragma unroll
  for (int rr = 0; rr < 8; ++rr) s4[SW(A5)] = v4[rr];
  __syncthreads();

  // ---- S6: window {0,1,2,3,4}; store to global ----
#pragma unroll
  for (int rr = 0; rr < 8; ++rr) v4[rr] = s4[SW(A6)];
  cnot32<3, 2>(v); cnot32<2, 1>(v); cnot32<1, 0>(v);   // C(3,2) C(2,1) C(1,0)
  ry32<3>(v, SHC(17)); ry32<2>(v, SHC(18)); ry32<1>(v, SHC(19)); // q17,q18,q19
#pragma unroll
  for (int rr = 0; rr < 8; ++rr) g4[A6] = v4[rr];
}

// ---------------- H pass: tile = bits {0..5,13..20}, t = bits 6..12 ----------------
// local l0..l5 = g0..g5, l6..l13 = g13..g20; global f4 index:
#define GH(l4) (((l4) & 0xF) | (t << 4) | (((l4) >> 4) << 11))

__global__ __launch_bounds__(512, 4) void k_H(const float* __restrict__ w,
                                              float* __restrict__ st) {
  __shared__ __align__(16) float s[16384];
  float4* s4 = reinterpret_cast<float4*>(s);
  const int tid = threadIdx.x;
  const int b = blockIdx.x >> 7, t = blockIdx.x & 127;
  const int lane = tid & 63;
  float cv = 1.f, sv = 0.f;
  if (lane < NQ) sincosf(0.5f * w[lane], &sv, &cv);
  float4* g4 = reinterpret_cast<float4*>(st) + ((size_t)b << 19);
  float v[32];
  float4* v4 = reinterpret_cast<float4*>(v);

  // ---- A: window {l0,l1,l11,l12,l13} ----
#pragma unroll
  for (int rr = 0; rr < 8; ++rr) v4[rr] = g4[GH(A1)];
  cnot32<0, 4>(v);                            // wrap C(g0,g20) ctrl l0, tgt l13
  ry32<0>(v, SHC(20));                        // RY g0  (q20)
  ry32<4>(v, SHC(0));                         // RY l13=g20 (q0)
  ry32<3>(v, SHC(1));                         // RY l12=g19 (q1)
  ry32<2>(v, SHC(2));                         // RY l11=g18 (q2)
  cnot32<4, 3>(v); cnot32<3, 2>(v);           // next chain C(g20,g19) C(g19,g18)
#pragma unroll
  for (int rr = 0; rr < 8; ++rr) s4[SW(A1)] = v4[rr];
  __syncthreads();

  // ---- B: window {l0,l1,l9,l10,l11} ----
#pragma unroll
  for (int rr = 0; rr < 8; ++rr) v4[rr] = s4[SW(A2)];
  ry32<3>(v, SHC(3));                         // RY l10=g17 (q3)
  ry32<2>(v, SHC(4));                         // RY l9 =g16 (q4)
  cnot32<4, 3>(v); cnot32<3, 2>(v);           // C(g18,g17) C(g17,g16)
#pragma unroll
  for (int rr = 0; rr < 8; ++rr) s4[SW(A2)] = v4[rr];
  __syncthreads();

  // ---- C: window {l0,l1,l7,l8,l9} ----
#pragma unroll
  for (int rr = 0; rr < 8; ++rr) v4[rr] = s4[SW(A3)];
  ry32<3>(v, SHC(5));                         // RY l8=g15 (q5)
  ry32<2>(v, SHC(6));                         // RY l7=g14 (q6)
  cnot32<4, 3>(v); cnot32<3, 2>(v);           // C(g16,g15) C(g15,g14)
#pragma unroll
  for (int rr = 0; rr < 8; ++rr) s4[SW(A3)] = v4[rr];
  __syncthreads();

  // ---- D: window {l0,l1,l5,l6,l7}; store to global ----
#pragma unroll
  for (int rr = 0; rr < 8; ++rr) v4[rr] = s4[SW(A4)];
  cnot32<4, 3>(v);                            // C(g14,g13)
#pragma unroll
  for (int rr = 0; rr < 8; ++rr) g4[GH(A4)] = v4[rr];
}

// ---------------- final H pass + measurement ----------------
__global__ __launch_bounds__(512, 4) void k_Hfin(const float* __restrict__ w,
                                                 const float* __restrict__ st,
                                                 float* __restrict__ partial) {
  __shared__ __align__(16) float s[16384];
  float4* s4 = reinterpret_cast<float4*>(s);
  const int tid = threadIdx.x;
  const int b = blockIdx.x >> 7, t = blockIdx.x & 127;
  const int lane = tid & 63;
  float cv = 1.f, sv = 0.f;
  if (lane < NQ) sincosf(0.5f * w[lane], &sv, &cv);
  const float4* g4 = reinterpret_cast<const float4*>(st) + ((size_t)b << 19);
  float v[32];
  float4* v4 = reinterpret_cast<float4*>(v);

  // ---- A ----
#pragma unroll
  for (int rr = 0; rr < 8; ++rr) v4[rr] = g4[GH(A1)];
  cnot32<0, 4>(v);
  ry32<0>(v, SHC(20)); ry32<4>(v, SHC(0)); ry32<3>(v, SHC(1)); ry32<2>(v, SHC(2));
#pragma unroll
  for (int rr = 0; rr < 8; ++rr) s4[SW(A1)] = v4[rr];
  __syncthreads();

  // ---- B ----
#pragma unroll
  for (int rr = 0; rr < 8; ++rr) v4[rr] = s4[SW(A2)];
  ry32<3>(v, SHC(3)); ry32<2>(v, SHC(4));
#pragma unroll
  for (int rr = 0; rr < 8; ++rr) s4[SW(A2)] = v4[rr];
  __syncthreads();

  // ---- C: window {l0,l1,l7,l8,l9} -> reg bits q20,q19,q6,q5,q4 ----
#pragma unroll
  for (int rr = 0; rr < 8; ++rr) v4[rr] = s4[SW(A3)];
  __syncthreads();   // all LDS reads done; s reused for reduction below
  ry32<3>(v, SHC(5)); ry32<2>(v, SHC(6));

  float S = 0, aq20 = 0, aq19 = 0, aq6 = 0, aq5 = 0, aq4 = 0;
#pragma unroll
  for (int r = 0; r < 32; ++r) {
    float p = v[r] * v[r];
    S += p;
    aq20 += (r & 1)  ? -p : p;   // r0 = l0  = g0  -> q20
    aq19 += (r & 2)  ? -p : p;   // r1 = l1  = g1  -> q19
    aq6  += (r & 4)  ? -p : p;   // r2 = l7  = g14 -> q6
    aq5  += (r & 8)  ? -p : p;   // r3 = l8  = g15 -> q5
    aq4  += (r & 16) ? -p : p;   // r4 = l9  = g16 -> q4
  }
  float a21[21];
  a21[20] = aq20; a21[19] = aq19; a21[6] = aq6; a21[5] = aq5; a21[4] = aq4;
  a21[18] = (tid & 1)   ? -S : S;  // l2  = g2  -> q18
  a21[17] = (tid & 2)   ? -S : S;  // l3  = g3  -> q17
  a21[16] = (tid & 4)   ? -S : S;  // l4  = g4  -> q16
  a21[15] = (tid & 8)   ? -S : S;  // l5  = g5  -> q15
  a21[7]  = (tid & 16)  ? -S : S;  // l6  = g13 -> q7
  a21[3]  = (tid & 32)  ? -S : S;  // l10 = g17 -> q3
  a21[2]  = (tid & 64)  ? -S : S;  // l11 = g18 -> q2
  a21[1]  = (tid & 128) ? -S : S;  // l12 = g19 -> q1
  a21[0]  = (tid & 256) ? -S : S;  // l13 = g20 -> q0
  a21[14] = (t & 1)  ? -S : S;     // g6  -> q14
  a21[13] = (t & 2)  ? -S : S;
  a21[12] = (t & 4)  ? -S : S;
  a21[11] = (t & 8)  ? -S : S;
  a21[10] = (t & 16) ? -S : S;
  a21[9]  = (t & 32) ? -S : S;
  a21[8]  = (t & 64) ? -S : S;     // g12 -> q8

  const int wv = tid >> 6;
#pragma unroll
  for (int q = 0; q < 21; ++q) {
    float val = a21[q];
    val += __shfl_down(val, 32);
    val += __shfl_down(val, 16);
    val += __shfl_down(val, 8);
    val += __shfl_down(val, 4);
    val += __shfl_down(val, 2);
    val += __shfl_down(val, 1);
    if (lane == 0) s[q * 8 + wv] = val;
  }
  __syncthreads();
  if (tid < NQ) {
    float sum = 0.f;
#pragma unroll
    for (int k = 0; k < 8; ++k) sum += s[tid * 8 + k];
    partial[blockIdx.x * NQ + tid] = sum;
  }
}

// ---------------- deterministic final reduction ----------------
__global__ void k_red(const float* __restrict__ partial, float* __restrict__ out) {
  int tid = threadIdx.x;
  if (tid < 84) {
    int b = tid / NQ, q = tid % NQ;
    float sum = 0.f;
    for (int k = 0; k < 128; ++k) sum += partial[(b * 128 + k) * NQ + q];
    out[tid] = sum;     // tid == b*21 + q
  }
}

extern "C" void kernel_launch(void* const* d_in, const int* in_sizes, int n_in,
                              void* d_out, int out_size, void* d_ws, size_t ws_size,
                              hipStream_t stream) {
  const float* x = (const float*)d_in[0];   // (4,21) f32
  const float* w = (const float*)d_in[1];   // (3,21) f32
  float* out = (float*)d_out;               // (4,21) f32
  float* st = (float*)d_ws;                 // 4 * 2^21 f32
  float* partial = st + ((size_t)4 << 21);  // 512*21 f32
  if (ws_size < ((size_t)4 << 21) * 4 + 512 * 21 * 4) return;

  dim3 grid(512), blk(512);
  k_L<true> <<<grid, blk, 0, stream>>>(x, w +  0, st);
  k_H       <<<grid, blk, 0, stream>>>(w +  0, st);
  k_L<false><<<grid, blk, 0, stream>>>(nullptr, w + 21, st);
  k_H       <<<grid, blk, 0, stream>>>(w + 21, st);
  k_L<false><<<grid, blk, 0, stream>>>(nullptr, w + 42, st);
  k_Hfin    <<<grid, blk, 0, stream>>>(w + 42, st, partial);
  k_red     <<<1, dim3(128), 0, stream>>>(partial, out);
}